// Round 6
// baseline (10978.708 us; speedup 1.0000x reference)
//
#include <hip/hip_runtime.h>

// B=64, T=128, U=256, D_in=32, SKIP=4; dense: (64 x 32768) @ (32768 x 4096)

__device__ __forceinline__ float sigmoidf_(float x) {
    return 1.0f / (1.0f + __expf(-x));
}
__device__ __forceinline__ float tanhf_(float x) {
    float xc = fminf(fmaxf(x, -15.f), 15.f);
    float e = __expf(2.f * xc);
    return (e - 1.f) / (e + 1.f);
}

// ---------------- weight packing (all fp32) ----------------
__global__ __launch_bounds__(256) void pack_w4(
    const float* __restrict__ enc_rk, const float* __restrict__ dec_rk,
    const float* __restrict__ dec_k,  const float* __restrict__ enc_k,
    float4* __restrict__ rk4e, float4* __restrict__ rk4d,
    float4* __restrict__ dk4,  float4* __restrict__ ek4)
{
    int r = blockIdx.x, v = threadIdx.x;
    const float* src; float4* dst; int row;
    if (r < 256)      { src = enc_rk; dst = rk4e; row = r; }
    else if (r < 512) { src = dec_rk; dst = rk4d; row = r - 256; }
    else if (r < 768) { src = dec_k;  dst = dk4;  row = r - 512; }
    else              { src = enc_k;  dst = ek4;  row = r - 768; }
    const float* s = src + row * 1024;
    dst[row * 256 + v] = make_float4(s[v], s[256 + v], s[512 + v], s[768 + v]);
}

// ---------------- xW GEMM (enc: K=32 rows gathered from X[:,0]; dec: K=256 from SE) ----------------
__global__ __launch_bounds__(256) void xw_gemm2(
    const float*  __restrict__ src,
    const float4* __restrict__ wk4,
    const float*  __restrict__ bias,
    float4* __restrict__ xWp,
    int K, int encmode)
{
    const int v = threadIdx.x;
    const int r0 = blockIdx.x * 16;
    __shared__ float se[16][256];

    if (encmode) {
        #pragma unroll
        for (int p = 0; p < 2; ++p) {
            int idx = p * 256 + v;
            int rr = idx >> 5, d = idx & 31;
            int R = r0 + rr, b = R >> 7, t = R & 127;
            se[rr][d] = src[((size_t)b * 129 * 128 + t) * 32 + d];
        }
    } else {
        #pragma unroll
        for (int rr = 0; rr < 16; ++rr)
            se[rr][v] = src[(size_t)(r0 + rr) * 256 + v];
    }
    __syncthreads();

    float4 bv = make_float4(bias[v], bias[256 + v], bias[512 + v], bias[768 + v]);
    float4 acc[16];
    #pragma unroll
    for (int rr = 0; rr < 16; ++rr) acc[rr] = bv;

    #pragma unroll 4
    for (int u = 0; u < K; ++u) {
        float4 w = wk4[u * 256 + v];
        #pragma unroll
        for (int rr = 0; rr < 16; ++rr) {
            float s = se[rr][u];
            acc[rr].x += s * w.x; acc[rr].y += s * w.y;
            acc[rr].z += s * w.z; acc[rr].w += s * w.w;
        }
    }
    #pragma unroll
    for (int rr = 0; rr < 16; ++rr)
        xWp[(size_t)(r0 + rr) * 256 + v] = acc[rr];
}

// ---------------- zero G[0], HR[1..4], barrier counter ----------------
__global__ __launch_bounds__(256) void zero_state(
    float* __restrict__ G0, float* __restrict__ HR14, unsigned* __restrict__ cnt)
{
    int bx = blockIdx.x, i = bx * 256 + threadIdx.x;
    if (bx < 256)      G0[i] = 0.f;
    else if (bx < 512) HR14[i - 65536] = 0.f;
    else if (threadIdx.x < 16) cnt[threadIdx.x] = 0u;
}

// ---------------- persistent v-split skip-LSTM recurrence ----------------
// 64 blocks = 4 batch-groups x 16 v-slices; weights LDS-resident for all 128 steps.
// G: [2][64][256] float4 gate state (double buffer); HR: [5][64][256] h ring (read t-4, write t).
// Grid barrier: monotonic counter, 64 arrivals per step.
__global__ __launch_bounds__(1024) void rec3(
    const float4* __restrict__ xW,     // (B*128*256) float4, bias included
    const float4* __restrict__ rk4,    // (256*256) packed gate weights
    const float*  __restrict__ k2,     // (256*256) skip weights
    const float*  __restrict__ bias2,
    const float*  __restrict__ s0p,
    float* __restrict__ out,           // (B*128*256)
    float4* __restrict__ G,
    float*  __restrict__ HR,
    unsigned* __restrict__ cnt)
{
    const int tid = threadIdx.x;
    const int bg  = blockIdx.x >> 4;   // 0..3 batch-group (16 b each)
    const int vs  = blockIdx.x & 15;   // 0..15 v-slice (16 v each)
    const int p   = tid >> 2;          // pair 0..255 = (bl, vl)
    const int us  = tid & 3;           // u-quarter
    const int bl  = p >> 4;
    const int vl  = p & 15;
    const int b   = bg * 16 + bl;
    const int v   = vs * 16 + vl;

    __shared__ float4 w4[256][16];     // 64 KB
    __shared__ float  k2l[256][16];    // 16 KB

    for (int i = tid; i < 4096; i += 1024) {
        int u = i >> 4, j = i & 15;
        w4[u][j]  = rk4[u * 256 + vs * 16 + j];
        k2l[u][j] = k2[u * 256 + vs * 16 + j];
    }
    __syncthreads();

    const float s0 = s0p[0];
    const float b2 = bias2[v];
    const bool  fin = (us == 0);
    float cst = 0.f;
    const int u0 = us * 64;

    for (int t = 0; t < 128; ++t) {
        const int rp = t & 1;
        const int sr = (t + 1) % 5;     // holds h[t-4]
        float4 xa = make_float4(0.f, 0.f, 0.f, 0.f);
        if (fin) xa = xW[((size_t)b * 128 + t) * 256 + v];

        const float4* gp = G  + ((size_t)rp * 64 + b) * 256;
        const float*  hp = HR + ((size_t)sr * 64 + b) * 256;

        float ai = 0.f, af = 0.f, ac = 0.f, ao = 0.f, as = 0.f;
        #pragma unroll 8
        for (int k = 0; k < 64; ++k) {
            int u = u0 + k;
            float4 g  = gp[u];
            float  hr = hp[u];
            float4 w  = w4[u][vl];
            float  kk = k2l[u][vl];
            ai += g.x * w.x; af += g.y * w.y; ac += g.z * w.z; ao += g.w * w.w;
            as += hr * kk;
        }
        // reduce u-quarters across the 4 consecutive lanes of the pair
        ai += __shfl_xor(ai, 1, 4); ai += __shfl_xor(ai, 2, 4);
        af += __shfl_xor(af, 1, 4); af += __shfl_xor(af, 2, 4);
        ac += __shfl_xor(ac, 1, 4); ac += __shfl_xor(ac, 2, 4);
        ao += __shfl_xor(ao, 1, 4); ao += __shfl_xor(ao, 2, 4);
        as += __shfl_xor(as, 1, 4); as += __shfl_xor(as, 2, 4);

        if (fin) {
            float gi = sigmoidf_(xa.x + ai);
            float gf = sigmoidf_(xa.y + af);
            float cb = tanhf_(xa.z + ac);
            cst = gf * cst + gi * cb;
            float go = sigmoidf_(xa.w + ao);
            float hh = go * tanhf_(cst);
            float hs = sigmoidf_(as + b2);
            float hf = s0 * hh + (1.f - s0) * hs;
            G[((size_t)(rp ^ 1) * 64 + b) * 256 + v] = make_float4(gi, gf, cst, go);
            HR[((size_t)(t % 5) * 64 + b) * 256 + v] = hf;
            out[((size_t)b * 128 + t) * 256 + v] = hf;
        }

        if (t < 127) {
            __syncthreads();               // all block writes drained (vmcnt before barrier)
            if (tid == 0) {
                __threadfence();           // release: flush to device coherence point
                atomicAdd(cnt, 1u);
                unsigned tgt = 64u * (unsigned)(t + 1);
                while (atomicAdd(cnt, 0u) < tgt) __builtin_amdgcn_s_sleep(1);
                __threadfence();           // acquire: invalidate stale cache
            }
            __syncthreads();
        }
    }
}

// ---------------- SD transpose: (64 x 32768) -> SDT (32768 x 64) ----------------
__global__ __launch_bounds__(256) void transp(const float* __restrict__ SD, float* __restrict__ SDT)
{
    const int k0 = blockIdx.x * 64;
    const int tid = threadIdx.x;
    __shared__ float t[64][65];
    #pragma unroll
    for (int i = 0; i < 4; ++i) {
        int idx = i * 256 + tid;
        int r = idx >> 4, c4 = (idx & 15) * 4;
        float4 x = *reinterpret_cast<const float4*>(SD + (size_t)r * 32768 + k0 + c4);
        t[r][c4] = x.x; t[r][c4 + 1] = x.y; t[r][c4 + 2] = x.z; t[r][c4 + 3] = x.w;
    }
    __syncthreads();
    #pragma unroll
    for (int i = 0; i < 4; ++i) {
        int idx = i * 256 + tid;
        int k = idx >> 4, r4 = (idx & 15) * 4;
        float4 o = make_float4(t[r4][k], t[r4 + 1][k], t[r4 + 2][k], t[r4 + 3][k]);
        *reinterpret_cast<float4*>(SDT + (size_t)(k0 + k) * 64 + r4) = o;
    }
}

// ---------------- dense split-K partials: grid = 64 col-tiles x 8 k-chunks ----------------
__global__ __launch_bounds__(256) void dense_partial(
    const float* __restrict__ SDT,   // (32768 x 64)
    const float* __restrict__ dw,    // (32768 x 4096)
    float* __restrict__ P)           // (8 x 64 x 4096)
{
    const int tid = threadIdx.x;
    const int ct = blockIdx.x & 63;
    const int kc = blockIdx.x >> 6;
    const int jq = tid & 15;
    const int rg = tid >> 4;
    const int j0 = ct * 64 + jq * 4;
    const int r0 = rg * 4;

    const float* sp = SDT + (size_t)kc * 4096 * 64 + r0;
    const float* wp = dw + (size_t)kc * 4096 * 4096 + j0;

    float4 a0 = make_float4(0.f,0.f,0.f,0.f), a1 = a0, a2 = a0, a3 = a0;
    #pragma unroll 8
    for (int kk = 0; kk < 4096; ++kk) {
        float4 s4 = *reinterpret_cast<const float4*>(sp + (size_t)kk * 64);
        float4 w4 = *reinterpret_cast<const float4*>(wp + (size_t)kk * 4096);
        a0.x += s4.x * w4.x; a0.y += s4.x * w4.y; a0.z += s4.x * w4.z; a0.w += s4.x * w4.w;
        a1.x += s4.y * w4.x; a1.y += s4.y * w4.y; a1.z += s4.y * w4.z; a1.w += s4.y * w4.w;
        a2.x += s4.z * w4.x; a2.y += s4.z * w4.y; a2.z += s4.z * w4.z; a2.w += s4.z * w4.w;
        a3.x += s4.w * w4.x; a3.y += s4.w * w4.y; a3.z += s4.w * w4.z; a3.w += s4.w * w4.w;
    }
    float* p0 = P + ((size_t)(kc * 64 + r0) * 4096) + j0;
    *reinterpret_cast<float4*>(p0)               = a0;
    *reinterpret_cast<float4*>(p0 + 4096)        = a1;
    *reinterpret_cast<float4*>(p0 + 2 * 4096)    = a2;
    *reinterpret_cast<float4*>(p0 + 3 * 4096)    = a3;
}

// ---------------- reduce partials + bias + Z2 ----------------
__global__ __launch_bounds__(256) void reduce_z2(
    const float* __restrict__ P,
    const float* __restrict__ db,
    const float* __restrict__ X,
    const float* __restrict__ fw,
    const float* __restrict__ fbp,
    float* __restrict__ out)
{
    const int o4 = blockIdx.x * 256 + threadIdx.x;   // 0..65535
    const int b  = o4 >> 10;
    const int j4 = o4 & 1023;
    const int j0 = j4 * 4;
    const int i  = j0 >> 5;
    const int m  = j0 & 31;

    float4 acc = *reinterpret_cast<const float4*>(db + j0);
    #pragma unroll
    for (int kc = 0; kc < 8; ++kc) {
        float4 p = *reinterpret_cast<const float4*>(P + (size_t)(kc * 64 + b) * 4096 + j0);
        acc.x += p.x; acc.y += p.y; acc.z += p.z; acc.w += p.w;
    }

    const float* xp = X + ((size_t)(b * 129 + 1 + i) * 128) * 32 + m;
    #pragma unroll 8
    for (int s = 0; s < 128; ++s) {
        float4 xv = *reinterpret_cast<const float4*>(xp + (size_t)s * 32);
        float w = fw[s];
        acc.x += w * xv.x; acc.y += w * xv.y; acc.z += w * xv.z; acc.w += w * xv.w;
    }
    const float fb = fbp[0];
    acc.x += fb; acc.y += fb; acc.z += fb; acc.w += fb;
    *reinterpret_cast<float4*>(out + (size_t)o4 * 4) = acc;
}

extern "C" void kernel_launch(void* const* d_in, const int* in_sizes, int n_in,
                              void* d_out, int out_size, void* d_ws, size_t ws_size,
                              hipStream_t stream) {
    const float* X    = (const float*)d_in[0];
    const float* e_k  = (const float*)d_in[1];
    const float* e_rk = (const float*)d_in[2];
    const float* e_k2 = (const float*)d_in[3];
    const float* e_b  = (const float*)d_in[4];
    const float* e_b2 = (const float*)d_in[5];
    const float* e_s0 = (const float*)d_in[6];
    const float* d_k  = (const float*)d_in[7];
    const float* d_rk = (const float*)d_in[8];
    const float* d_k2 = (const float*)d_in[9];
    const float* d_b  = (const float*)d_in[10];
    const float* d_b2 = (const float*)d_in[11];
    const float* d_s0 = (const float*)d_in[12];
    const float* dw   = (const float*)d_in[13];
    const float* db   = (const float*)d_in[14];
    const float* fw   = (const float*)d_in[15];
    const float* fb   = (const float*)d_in[16];

    float* ws = (float*)d_ws;
    // workspace layout (float offsets):
    // 0: rk4e[262144] | 262144: rk4d[262144] | 524288: dk4[262144] | 786432: ek4[32768]
    // 819200: G[131072] | 950272: HR[81920] | 1032192: cnt[16]
    // 1048576: xW[8M] (reused as P) | 9437184: SE[2M] (reused as SDT) | 11534336: SD[2M]
    float4*   rk4e = (float4*)(ws);
    float4*   rk4d = (float4*)(ws + 262144);
    float4*   dk4  = (float4*)(ws + 524288);
    float4*   ek4  = (float4*)(ws + 786432);
    float*    Gf   = ws + 819200;
    float*    HRf  = ws + 950272;
    unsigned* cnt  = (unsigned*)(ws + 1032192);
    float*    xW   = ws + 1048576;
    float*    SE   = ws + 9437184;
    float*    SD   = ws + 11534336;

    float* P   = xW;
    float* SDT = SE;

    hipLaunchKernelGGL(pack_w4, dim3(800), dim3(256), 0, stream,
                       e_rk, d_rk, d_k, e_k, rk4e, rk4d, dk4, ek4);
    hipLaunchKernelGGL(xw_gemm2, dim3(512), dim3(256), 0, stream,
                       X, ek4, e_b, (float4*)xW, 32, 1);
    hipLaunchKernelGGL(zero_state, dim3(513), dim3(256), 0, stream,
                       Gf, HRf + 16384, cnt);
    hipLaunchKernelGGL(rec3, dim3(64), dim3(1024), 0, stream,
                       (const float4*)xW, rk4e, e_k2, e_b2, e_s0, SE,
                       (float4*)Gf, HRf, cnt);
    hipLaunchKernelGGL(xw_gemm2, dim3(512), dim3(256), 0, stream,
                       SE, dk4, d_b, (float4*)xW, 256, 0);
    hipLaunchKernelGGL(zero_state, dim3(513), dim3(256), 0, stream,
                       Gf, HRf + 16384, cnt);
    hipLaunchKernelGGL(rec3, dim3(64), dim3(1024), 0, stream,
                       (const float4*)xW, rk4d, d_k2, d_b2, d_s0, SD,
                       (float4*)Gf, HRf, cnt);
    hipLaunchKernelGGL(transp, dim3(512), dim3(256), 0, stream, SD, SDT);
    hipLaunchKernelGGL(dense_partial, dim3(512), dim3(256), 0, stream, SDT, dw, P);
    hipLaunchKernelGGL(reduce_z2, dim3(256), dim3(256), 0, stream,
                       P, db, X, fw, fb, (float*)d_out);
}

// Round 8
// 2865.802 us; speedup vs baseline: 3.8309x; 3.8309x over previous
//
#include <hip/hip_runtime.h>
#include <hip/hip_fp16.h>

// B=64, T=128, U=256, D_in=32, SKIP=4; dense: (64 x 32768) @ (32768 x 4096)

__device__ __forceinline__ float sigmoidf_(float x) {
    return 1.0f / (1.0f + __expf(-x));
}
__device__ __forceinline__ float tanhf_(float x) {
    float xc = fminf(fmaxf(x, -15.f), 15.f);
    float e = __expf(2.f * xc);
    return (e - 1.f) / (e + 1.f);
}
__device__ __forceinline__ unsigned pkh(float lo, float hi) {
    __half2 h = __halves2half2(__float2half(lo), __float2half(hi));
    return *reinterpret_cast<unsigned*>(&h);
}
__device__ __forceinline__ float2 uph(unsigned u) {
    __half2 h = *reinterpret_cast<__half2*>(&u);
    return __half22float2(h);
}

// ---------------- all weight packing in one dispatch ----------------
// rk4e/rk4d/dk4/ek4 per (u,v): float4{W[u][v], W[u][256+v], W[u][512+v], W[u][768+v]} (fp32)
// kh2e/kh2d per (u2,v): half2{k2[2u2][v], k2[2u2+1][v]}  (fp16, skip path only)
__global__ __launch_bounds__(256) void packall(
    const float* __restrict__ e_rk, const float* __restrict__ d_rk,
    const float* __restrict__ d_k,  const float* __restrict__ e_k,
    const float* __restrict__ e_k2, const float* __restrict__ d_k2,
    float4* __restrict__ rk4e, float4* __restrict__ rk4d,
    float4* __restrict__ dk4,  float4* __restrict__ ek4,
    unsigned* __restrict__ kh2e, unsigned* __restrict__ kh2d)
{
    const int bx = blockIdx.x, v = threadIdx.x;
    if (bx < 800) {
        const float* src; float4* dst; int row;
        if (bx < 256)      { src = e_rk; dst = rk4e; row = bx; }
        else if (bx < 512) { src = d_rk; dst = rk4d; row = bx - 256; }
        else if (bx < 768) { src = d_k;  dst = dk4;  row = bx - 512; }
        else               { src = e_k;  dst = ek4;  row = bx - 768; }
        const float* s = src + (size_t)row * 1024;
        dst[row * 256 + v] = make_float4(s[v], s[256 + v], s[512 + v], s[768 + v]);
    } else {
        const int u2 = bx - 800;   // 0..127
        kh2e[u2 * 256 + v] = pkh(e_k2[(2 * u2) * 256 + v], e_k2[(2 * u2 + 1) * 256 + v]);
        kh2d[u2 * 256 + v] = pkh(d_k2[(2 * u2) * 256 + v], d_k2[(2 * u2 + 1) * 256 + v]);
    }
}

// ---------------- enc xW GEMM: K=32 rows gathered from X[:,0] ----------------
__global__ __launch_bounds__(256) void xw_gemm_enc(
    const float*  __restrict__ X,
    const float4* __restrict__ ek4,
    const float*  __restrict__ bias,
    float4* __restrict__ xWp)
{
    const int v = threadIdx.x;
    const int r0 = blockIdx.x * 16;
    __shared__ float se[16][32];

    #pragma unroll
    for (int p = 0; p < 2; ++p) {
        int idx = p * 256 + v;
        int rr = idx >> 5, d = idx & 31;
        int R = r0 + rr, b = R >> 7, t = R & 127;
        se[rr][d] = X[((size_t)b * 129 * 128 + t) * 32 + d];   // X[b,0,t,d]
    }
    __syncthreads();

    float4 bv = make_float4(bias[v], bias[256 + v], bias[512 + v], bias[768 + v]);
    float4 acc[16];
    #pragma unroll
    for (int rr = 0; rr < 16; ++rr) acc[rr] = bv;

    #pragma unroll
    for (int u = 0; u < 32; ++u) {
        float4 w = ek4[u * 256 + v];
        #pragma unroll
        for (int rr = 0; rr < 16; ++rr) {
            float s = se[rr][u];
            acc[rr].x += s * w.x; acc[rr].y += s * w.y;
            acc[rr].z += s * w.z; acc[rr].w += s * w.w;
        }
    }
    #pragma unroll
    for (int rr = 0; rr < 16; ++rr)
        xWp[(size_t)(r0 + rr) * 256 + v] = acc[rr];
}

// ---------------- dec xW GEMM: 32 rows/block, 512 threads ----------------
__global__ __launch_bounds__(512) void xw_gemm_dec(
    const float*  __restrict__ SE,
    const float4* __restrict__ dk4,
    const float*  __restrict__ bias,
    float4* __restrict__ xWp)
{
    const int tid = threadIdx.x;
    const int v = tid & 255;
    const int hh = tid >> 8;               // 0/1
    const int rbase = blockIdx.x * 32;
    __shared__ float se[32][256];

    for (int i = tid; i < 8192; i += 512) {
        int rr = i >> 8, c = i & 255;
        se[rr][c] = SE[(size_t)(rbase + rr) * 256 + c];
    }
    __syncthreads();

    float4 bv = make_float4(bias[v], bias[256 + v], bias[512 + v], bias[768 + v]);
    float4 acc[16];
    #pragma unroll
    for (int rr = 0; rr < 16; ++rr) acc[rr] = bv;

    #pragma unroll 8
    for (int u = 0; u < 256; ++u) {
        float4 w = dk4[u * 256 + v];
        #pragma unroll
        for (int rr = 0; rr < 16; ++rr) {
            float s = se[hh * 16 + rr][u];
            acc[rr].x += s * w.x; acc[rr].y += s * w.y;
            acc[rr].z += s * w.z; acc[rr].w += s * w.w;
        }
    }
    #pragma unroll
    for (int rr = 0; rr < 16; ++rr)
        xWp[(size_t)(rbase + hh * 16 + rr) * 256 + v] = acc[rr];
}

// ---------------- skip-LSTM recurrence ----------------
// 1 block/batch, 1024 threads, u-split x4. fp32 gate weights (24 u-rows LDS-resident,
// 232 streamed), fp16 skip weights packed in pairs.
__global__ __launch_bounds__(1024) void rec2f(
    const float4*   __restrict__ xW,    // (B*128*256) float4, bias included
    const float4*   __restrict__ rk4,   // (256*256) fp32 gate weights
    const unsigned* __restrict__ kh2,   // (128*256) fp16 skip-weight pairs
    const float*    __restrict__ bias2,
    const float*    __restrict__ s0p,
    float* __restrict__ out)            // (B*128*256)
{
    const int b   = blockIdx.x;
    const int tid = threadIdx.x;
    const int v   = tid & 255;
    const int c   = tid >> 8;   // 0..3 u-chunk

    __shared__ float4   wres[24][256];   // 96 KB: rows c*64+0..5 per chunk
    __shared__ unsigned kres[12][256];   // 12 KB: k2 pairs c*32+0..2 per chunk
    __shared__ float4 h4[256];
    __shared__ float  pq[4][256];
    __shared__ float4 pA[4][256];
    __shared__ float  pS[4][256];

    for (int i = tid; i < 6144; i += 1024) {
        int ridx = i >> 8, vv = i & 255;
        int cc = ridx / 6, j = ridx - cc * 6;
        wres[ridx][vv] = rk4[(cc * 64 + j) * 256 + vv];
    }
    for (int i = tid; i < 3072; i += 1024) {
        int pidx = i >> 8, vv = i & 255;
        int cc = pidx / 3, jp = pidx - cc * 3;
        kres[pidx][vv] = kh2[(cc * 32 + jp) * 256 + vv];
    }
    if (tid < 256) {
        h4[v] = make_float4(0.f, 0.f, 0.f, 0.f);
        pq[0][v] = 0.f; pq[1][v] = 0.f; pq[2][v] = 0.f; pq[3][v] = 0.f;
    }
    float cst = 0.f;
    const float s0 = s0p[0];
    const float b2 = bias2[v];
    __syncthreads();

    const float4*   wp = rk4 + (c * 64 + 6) * 256 + v;   // 58 streamed rows
    const unsigned* kp = kh2 + (c * 32 + 3) * 256 + v;   // 29 streamed pairs
    const int ub = c * 64;

    for (int t = 0; t < 128; ++t) {
        const int slot = t & 3;
        float4 xa = make_float4(0.f, 0.f, 0.f, 0.f);
        if (tid < 256) xa = xW[(size_t)(b * 128 + t) * 256 + v];

        float ai = 0.f, af = 0.f, acg = 0.f, ao = 0.f, as = 0.f;
        // resident 3 pairs (u-rows ub..ub+5)
        #pragma unroll
        for (int jp = 0; jp < 3; ++jp) {
            float4 wA = wres[c * 6 + 2 * jp][v];
            float4 wB = wres[c * 6 + 2 * jp + 1][v];
            float2 kk = uph(kres[c * 3 + jp][v]);
            float4 hA = h4[ub + 2 * jp];
            float4 hB = h4[ub + 2 * jp + 1];
            float  pa = pq[slot][ub + 2 * jp];
            float  pb = pq[slot][ub + 2 * jp + 1];
            ai  += hA.x * wA.x + hB.x * wB.x;
            af  += hA.y * wA.y + hB.y * wB.y;
            acg += hA.z * wA.z + hB.z * wB.z;
            ao  += hA.w * wA.w + hB.w * wB.w;
            as  += pa * kk.x + pb * kk.y;
        }
        // streamed 29 pairs (u-rows ub+6..ub+63)
        #pragma unroll 8
        for (int up = 0; up < 29; ++up) {
            float4 wA = wp[(2 * up) * 256];
            float4 wB = wp[(2 * up + 1) * 256];
            float2 kk = uph(kp[up * 256]);
            float4 hA = h4[ub + 6 + 2 * up];
            float4 hB = h4[ub + 7 + 2 * up];
            float  pa = pq[slot][ub + 6 + 2 * up];
            float  pb = pq[slot][ub + 7 + 2 * up];
            ai  += hA.x * wA.x + hB.x * wB.x;
            af  += hA.y * wA.y + hB.y * wB.y;
            acg += hA.z * wA.z + hB.z * wB.z;
            ao  += hA.w * wA.w + hB.w * wB.w;
            as  += pa * kk.x + pb * kk.y;
        }
        pA[c][v] = make_float4(ai, af, acg, ao);
        pS[c][v] = as;
        __syncthreads();
        if (tid < 256) {
            float4 A0 = pA[0][v], A1 = pA[1][v], A2 = pA[2][v], A3 = pA[3][v];
            float  S  = pS[0][v] + pS[1][v] + pS[2][v] + pS[3][v];
            float gi = sigmoidf_(xa.x + A0.x + A1.x + A2.x + A3.x);
            float gf = sigmoidf_(xa.y + A0.y + A1.y + A2.y + A3.y);
            float cb = tanhf_(xa.z + A0.z + A1.z + A2.z + A3.z);
            cst = gf * cst + gi * cb;
            float go = sigmoidf_(xa.w + A0.w + A1.w + A2.w + A3.w);
            float hh = go * tanhf_(cst);
            float hs = sigmoidf_(S + b2);
            float hf = s0 * hh + (1.f - s0) * hs;
            h4[v] = make_float4(gi, gf, cst, go);
            pq[slot][v] = hf;
            out[(size_t)(b * 128 + t) * 256 + v] = hf;
        }
        __syncthreads();
    }
}

// ---------------- SD transpose: (64 x 32768) -> SDT (32768 x 64) ----------------
__global__ __launch_bounds__(256) void transp(const float* __restrict__ SD, float* __restrict__ SDT)
{
    const int k0 = blockIdx.x * 64;
    const int tid = threadIdx.x;
    __shared__ float t[64][65];
    #pragma unroll
    for (int i = 0; i < 4; ++i) {
        int idx = i * 256 + tid;
        int r = idx >> 4, c4 = (idx & 15) * 4;
        float4 x = *reinterpret_cast<const float4*>(SD + (size_t)r * 32768 + k0 + c4);
        t[r][c4] = x.x; t[r][c4 + 1] = x.y; t[r][c4 + 2] = x.z; t[r][c4 + 3] = x.w;
    }
    __syncthreads();
    #pragma unroll
    for (int i = 0; i < 4; ++i) {
        int idx = i * 256 + tid;
        int k = idx >> 4, r4 = (idx & 15) * 4;
        float4 o = make_float4(t[r4][k], t[r4 + 1][k], t[r4 + 2][k], t[r4 + 3][k]);
        *reinterpret_cast<float4*>(SDT + (size_t)(k0 + k) * 64 + r4) = o;
    }
}

// ---------------- dense split-K partials: grid = 64 col-tiles x 16 k-chunks ----------------
__global__ __launch_bounds__(256) void dense_partial(
    const float* __restrict__ SDT,   // (32768 x 64)
    const float* __restrict__ dw,    // (32768 x 4096)
    float* __restrict__ P)           // (16 x 64 x 4096)
{
    const int tid = threadIdx.x;
    const int ct = blockIdx.x & 63;
    const int kc = blockIdx.x >> 6;   // 0..15
    const int jq = tid & 15;
    const int rg = tid >> 4;
    const int j0 = ct * 64 + jq * 4;
    const int r0 = rg * 4;

    const float* sp = SDT + (size_t)kc * 2048 * 64 + r0;
    const float* wp = dw + (size_t)kc * 2048 * 4096 + j0;

    float4 a0 = make_float4(0.f,0.f,0.f,0.f), a1 = a0, a2 = a0, a3 = a0;
    #pragma unroll 8
    for (int kk = 0; kk < 2048; ++kk) {
        float4 s4 = *reinterpret_cast<const float4*>(sp + (size_t)kk * 64);
        float4 w4 = *reinterpret_cast<const float4*>(wp + (size_t)kk * 4096);
        a0.x += s4.x * w4.x; a0.y += s4.x * w4.y; a0.z += s4.x * w4.z; a0.w += s4.x * w4.w;
        a1.x += s4.y * w4.x; a1.y += s4.y * w4.y; a1.z += s4.y * w4.z; a1.w += s4.y * w4.w;
        a2.x += s4.z * w4.x; a2.y += s4.z * w4.y; a2.z += s4.z * w4.z; a2.w += s4.z * w4.w;
        a3.x += s4.w * w4.x; a3.y += s4.w * w4.y; a3.z += s4.w * w4.z; a3.w += s4.w * w4.w;
    }
    float* p0 = P + ((size_t)(kc * 64 + r0) * 4096) + j0;
    *reinterpret_cast<float4*>(p0)               = a0;
    *reinterpret_cast<float4*>(p0 + 4096)        = a1;
    *reinterpret_cast<float4*>(p0 + 2 * 4096)    = a2;
    *reinterpret_cast<float4*>(p0 + 3 * 4096)    = a3;
}

// ---------------- reduce partials + bias + Z2 ----------------
__global__ __launch_bounds__(256) void reduce_z2(
    const float* __restrict__ P,
    const float* __restrict__ db,
    const float* __restrict__ X,
    const float* __restrict__ fw,
    const float* __restrict__ fbp,
    float* __restrict__ out)
{
    const int o4 = blockIdx.x * 256 + threadIdx.x;   // 0..65535
    const int b  = o4 >> 10;
    const int j4 = o4 & 1023;
    const int j0 = j4 * 4;
    const int i  = j0 >> 5;
    const int m  = j0 & 31;

    float4 acc = *reinterpret_cast<const float4*>(db + j0);
    #pragma unroll
    for (int kc = 0; kc < 16; ++kc) {
        float4 p = *reinterpret_cast<const float4*>(P + (size_t)(kc * 64 + b) * 4096 + j0);
        acc.x += p.x; acc.y += p.y; acc.z += p.z; acc.w += p.w;
    }

    const float* xp = X + ((size_t)(b * 129 + 1 + i) * 128) * 32 + m;
    #pragma unroll 8
    for (int s = 0; s < 128; ++s) {
        float4 xv = *reinterpret_cast<const float4*>(xp + (size_t)s * 32);
        float w = fw[s];
        acc.x += w * xv.x; acc.y += w * xv.y; acc.z += w * xv.z; acc.w += w * xv.w;
    }
    const float fb = fbp[0];
    acc.x += fb; acc.y += fb; acc.z += fb; acc.w += fb;
    *reinterpret_cast<float4*>(out + (size_t)o4 * 4) = acc;
}

extern "C" void kernel_launch(void* const* d_in, const int* in_sizes, int n_in,
                              void* d_out, int out_size, void* d_ws, size_t ws_size,
                              hipStream_t stream) {
    const float* X    = (const float*)d_in[0];
    const float* e_k  = (const float*)d_in[1];
    const float* e_rk = (const float*)d_in[2];
    const float* e_k2 = (const float*)d_in[3];
    const float* e_b  = (const float*)d_in[4];
    const float* e_b2 = (const float*)d_in[5];
    const float* e_s0 = (const float*)d_in[6];
    const float* d_k  = (const float*)d_in[7];
    const float* d_rk = (const float*)d_in[8];
    const float* d_k2 = (const float*)d_in[9];
    const float* d_b  = (const float*)d_in[10];
    const float* d_b2 = (const float*)d_in[11];
    const float* d_s0 = (const float*)d_in[12];
    const float* dw   = (const float*)d_in[13];
    const float* db   = (const float*)d_in[14];
    const float* fw   = (const float*)d_in[15];
    const float* fb   = (const float*)d_in[16];

    float* ws = (float*)d_ws;
    // workspace (float offsets):
    // rk4e 0 | rk4d 262144 | dk4 524288 | ek4 786432(+32768)
    // kh2e 819200(+32768) | kh2d 851968(+32768) -> 884736
    // xW 1048576 (8M, reused as P 4M) | SE 9437184 (2M, reused as SDT) | SD 11534336 (2M)
    float4*   rk4e = (float4*)(ws);
    float4*   rk4d = (float4*)(ws + 262144);
    float4*   dk4  = (float4*)(ws + 524288);
    float4*   ek4  = (float4*)(ws + 786432);
    unsigned* kh2e = (unsigned*)(ws + 819200);
    unsigned* kh2d = (unsigned*)(ws + 851968);
    float*    xW   = ws + 1048576;
    float*    SE   = ws + 9437184;
    float*    SD   = ws + 11534336;

    float* P   = xW;   // 16*64*4096 = 4M floats, xW dead by then
    float* SDT = SE;   // 32768*64 = 2M floats, SE dead by then

    hipLaunchKernelGGL(packall, dim3(928), dim3(256), 0, stream,
                       e_rk, d_rk, d_k, e_k, e_k2, d_k2,
                       rk4e, rk4d, dk4, ek4, kh2e, kh2d);
    hipLaunchKernelGGL(xw_gemm_enc, dim3(512), dim3(256), 0, stream,
                       X, ek4, e_b, (float4*)xW);
    hipLaunchKernelGGL(rec2f, dim3(64), dim3(1024), 0, stream,
                       (const float4*)xW, rk4e, kh2e, e_b2, e_s0, SE);
    hipLaunchKernelGGL(xw_gemm_dec, dim3(256), dim3(512), 0, stream,
                       SE, dk4, d_b, (float4*)xW);
    hipLaunchKernelGGL(rec2f, dim3(64), dim3(1024), 0, stream,
                       (const float4*)xW, rk4d, kh2d, d_b2, d_s0, SD);
    hipLaunchKernelGGL(transp, dim3(512), dim3(256), 0, stream, SD, SDT);
    hipLaunchKernelGGL(dense_partial, dim3(1024), dim3(256), 0, stream, SDT, dw, P);
    hipLaunchKernelGGL(reduce_z2, dim3(256), dim3(256), 0, stream,
                       P, db, X, fw, fb, (float*)d_out);
}

// Round 9
// 2017.626 us; speedup vs baseline: 5.4414x; 1.4204x over previous
//
#include <hip/hip_runtime.h>
#include <hip/hip_fp16.h>

// B=64, T=128, U=256, D_in=32, SKIP=4; dense: (64 x 32768) @ (32768 x 4096)

__device__ __forceinline__ float sigmoidf_(float x) {
    return 1.0f / (1.0f + __expf(-x));
}
__device__ __forceinline__ float tanhf_(float x) {
    float xc = fminf(fmaxf(x, -15.f), 15.f);
    float e = __expf(2.f * xc);
    return (e - 1.f) / (e + 1.f);
}
__device__ __forceinline__ unsigned pkh(float lo, float hi) {
    __half2 h = __halves2half2(__float2half(lo), __float2half(hi));
    return *reinterpret_cast<unsigned*>(&h);
}
__device__ __forceinline__ float2 uph(unsigned u) {
    __half2 h = *reinterpret_cast<__half2*>(&u);
    return __half22float2(h);
}

// ---------------- all weight packing in one dispatch ----------------
__global__ __launch_bounds__(256) void packall(
    const float* __restrict__ e_rk, const float* __restrict__ d_rk,
    const float* __restrict__ d_k,  const float* __restrict__ e_k,
    const float* __restrict__ e_k2, const float* __restrict__ d_k2,
    float4* __restrict__ rk4e, float4* __restrict__ rk4d,
    float4* __restrict__ dk4,  float4* __restrict__ ek4,
    unsigned* __restrict__ kh2e, unsigned* __restrict__ kh2d)
{
    const int bx = blockIdx.x, v = threadIdx.x;
    if (bx < 800) {
        const float* src; float4* dst; int row;
        if (bx < 256)      { src = e_rk; dst = rk4e; row = bx; }
        else if (bx < 512) { src = d_rk; dst = rk4d; row = bx - 256; }
        else if (bx < 768) { src = d_k;  dst = dk4;  row = bx - 512; }
        else               { src = e_k;  dst = ek4;  row = bx - 768; }
        const float* s = src + (size_t)row * 1024;
        dst[row * 256 + v] = make_float4(s[v], s[256 + v], s[512 + v], s[768 + v]);
    } else {
        const int u2 = bx - 800;   // 0..127
        kh2e[u2 * 256 + v] = pkh(e_k2[(2 * u2) * 256 + v], e_k2[(2 * u2 + 1) * 256 + v]);
        kh2d[u2 * 256 + v] = pkh(d_k2[(2 * u2) * 256 + v], d_k2[(2 * u2 + 1) * 256 + v]);
    }
}

// ---------------- enc xW GEMM: K=32 rows gathered from X[:,0] ----------------
__global__ __launch_bounds__(256) void xw_gemm_enc(
    const float*  __restrict__ X,
    const float4* __restrict__ ek4,
    const float*  __restrict__ bias,
    float4* __restrict__ xWp)
{
    const int v = threadIdx.x;
    const int r0 = blockIdx.x * 16;
    __shared__ float se[16][32];

    #pragma unroll
    for (int p = 0; p < 2; ++p) {
        int idx = p * 256 + v;
        int rr = idx >> 5, d = idx & 31;
        int R = r0 + rr, b = R >> 7, t = R & 127;
        se[rr][d] = X[((size_t)b * 129 * 128 + t) * 32 + d];   // X[b,0,t,d]
    }
    __syncthreads();

    float4 bv = make_float4(bias[v], bias[256 + v], bias[512 + v], bias[768 + v]);
    float4 acc[16];
    #pragma unroll
    for (int rr = 0; rr < 16; ++rr) acc[rr] = bv;

    #pragma unroll
    for (int u = 0; u < 32; ++u) {
        float4 w = ek4[u * 256 + v];
        #pragma unroll
        for (int rr = 0; rr < 16; ++rr) {
            float s = se[rr][u];
            acc[rr].x += s * w.x; acc[rr].y += s * w.y;
            acc[rr].z += s * w.z; acc[rr].w += s * w.w;
        }
    }
    #pragma unroll
    for (int rr = 0; rr < 16; ++rr)
        xWp[(size_t)(r0 + rr) * 256 + v] = acc[rr];
}

// ---------------- dec xW GEMM: 32 rows/block, 512 threads ----------------
__global__ __launch_bounds__(512) void xw_gemm_dec(
    const float*  __restrict__ SE,
    const float4* __restrict__ dk4,
    const float*  __restrict__ bias,
    float4* __restrict__ xWp)
{
    const int tid = threadIdx.x;
    const int v = tid & 255;
    const int hh = tid >> 8;               // 0/1
    const int rbase = blockIdx.x * 32;
    __shared__ float se[32][256];

    for (int i = tid; i < 8192; i += 512) {
        int rr = i >> 8, c = i & 255;
        se[rr][c] = SE[(size_t)(rbase + rr) * 256 + c];
    }
    __syncthreads();

    float4 bv = make_float4(bias[v], bias[256 + v], bias[512 + v], bias[768 + v]);
    float4 acc[16];
    #pragma unroll
    for (int rr = 0; rr < 16; ++rr) acc[rr] = bv;

    #pragma unroll 8
    for (int u = 0; u < 256; ++u) {
        float4 w = dk4[u * 256 + v];
        #pragma unroll
        for (int rr = 0; rr < 16; ++rr) {
            float s = se[hh * 16 + rr][u];
            acc[rr].x += s * w.x; acc[rr].y += s * w.y;
            acc[rr].z += s * w.z; acc[rr].w += s * w.w;
        }
    }
    #pragma unroll
    for (int rr = 0; rr < 16; ++rr)
        xWp[(size_t)(rbase + hh * 16 + rr) * 256 + v] = acc[rr];
}

// ---------------- zero exchange buffers + flags ----------------
__global__ __launch_bounds__(256) void zero_ex(float* __restrict__ EX, unsigned* __restrict__ flags)
{
    const int bx = blockIdx.x;
    if (bx < 640) EX[bx * 256 + threadIdx.x] = 0.f;
    else if (threadIdx.x < 128) flags[threadIdx.x] = 0u;
}

// ---------------- skip-LSTM recurrence: 128 blocks = 64 batch-pairs x 2 v-halves ----------------
// Each block: 1024 thr = 8 u-chunks x 128 v; 64 gate rows LDS-resident, 24 streamed/chunk.
// Per-step pairwise exchange of {gate-vec float4[128], h float[128]} via relaxed device-scope
// atomics (NO fences -> L2 weight stream stays warm). 2-slot parity protocol, flag = step count.
__global__ __launch_bounds__(1024) void rec4(
    const float4*   __restrict__ xW,    // (B*128*256) float4, bias included
    const float4*   __restrict__ rk4,   // (256*256) fp32 gate weights
    const unsigned* __restrict__ kh2,   // (128*256) fp16 skip-weight pairs
    const float*    __restrict__ bias2,
    const float*    __restrict__ s0p,
    float* __restrict__ out,            // (B*128*256)
    float* __restrict__ EX,             // [2][64][2][640] floats
    unsigned* __restrict__ flags)       // [64][2]
{
    const int pair = blockIdx.x & 63;   // batch b
    const int half = blockIdx.x >> 6;   // v-half
    const int voff = half << 7;
    const int poff = voff ^ 128;
    const int tid  = threadIdx.x;
    const int c    = tid >> 7;          // 0..7 u-chunk (32 u each)
    const int vl   = tid & 127;

    __shared__ float4 wres[64][128];    // 128 KB: rows c*32+0..7 per chunk
    __shared__ float4 pA[8][128];       // 16 KB
    __shared__ float  pS[8][128];       // 4 KB
    __shared__ float4 h4[256];          // 4 KB: full gate-state [i,f,c,o]
    __shared__ float  pq[4][256];       // 4 KB: full h ring

    for (int i = tid; i < 8192; i += 1024) {
        int r = i >> 7, v2 = i & 127;
        int cc = r >> 3, j = r & 7;
        wres[r][v2] = rk4[(cc * 32 + j) * 256 + voff + v2];
    }
    if (tid < 256) {
        h4[tid] = make_float4(0.f, 0.f, 0.f, 0.f);
        pq[0][tid] = 0.f; pq[1][tid] = 0.f; pq[2][tid] = 0.f; pq[3][tid] = 0.f;
    }
    float cst = 0.f;
    const float s0 = s0p[0];
    const float b2 = bias2[voff + vl];
    unsigned* pflag = flags + pair * 2 + (half ^ 1);
    unsigned* mflag = flags + pair * 2 + half;
    __syncthreads();

    for (int t = 0; t < 128; ++t) {
        // wait for partner's step t-1 output
        if (tid == 0 && t > 0) {
            while (__hip_atomic_load(pflag, __ATOMIC_RELAXED, __HIP_MEMORY_SCOPE_AGENT) < (unsigned)t)
                __builtin_amdgcn_s_sleep(8);
        }
        __syncthreads();
        // stage partner's h[t-1]/gates[t-1] from slot (t-1)&1  (t=0: pre-zeroed slot 1)
        {
            const int sp = (t + 1) & 1;
            const float* src = EX + (((size_t)sp * 64 + pair) * 2 + (half ^ 1)) * 640;
            if (tid < 256) {
                unsigned long long g = __hip_atomic_load(
                    (const unsigned long long*)src + tid, __ATOMIC_RELAXED, __HIP_MEMORY_SCOPE_AGENT);
                reinterpret_cast<unsigned long long*>(&h4[poff])[tid] = g;
            } else if (tid < 320) {
                int j = tid - 256;
                unsigned long long hv = __hip_atomic_load(
                    (const unsigned long long*)(src + 512) + j, __ATOMIC_RELAXED, __HIP_MEMORY_SCOPE_AGENT);
                union { unsigned long long u; float f[2]; } cv; cv.u = hv;
                pq[(t + 3) & 3][poff + 2 * j]     = cv.f[0];
                pq[(t + 3) & 3][poff + 2 * j + 1] = cv.f[1];
            }
        }
        float4 xa = make_float4(0.f, 0.f, 0.f, 0.f);
        if (tid < 128) xa = xW[((size_t)pair * 128 + t) * 256 + voff + vl];
        __syncthreads();

        // GEMV over my 32-u chunk for my v column
        float ai = 0.f, af = 0.f, acg = 0.f, ao = 0.f, as = 0.f;
        #pragma unroll
        for (int j = 0; j < 8; ++j) {
            float4 w = wres[c * 8 + j][vl];
            float4 g = h4[c * 32 + j];
            ai += g.x * w.x; af += g.y * w.y; acg += g.z * w.z; ao += g.w * w.w;
        }
        const float4* wp = rk4 + (c * 32 + 8) * 256 + voff + vl;
        #pragma unroll 8
        for (int j = 0; j < 24; ++j) {
            float4 w = wp[j * 256];
            float4 g = h4[c * 32 + 8 + j];
            ai += g.x * w.x; af += g.y * w.y; acg += g.z * w.z; ao += g.w * w.w;
        }
        const unsigned* kp = kh2 + (c * 16) * 256 + voff + vl;
        const int slot = t & 3;
        #pragma unroll
        for (int j = 0; j < 16; ++j) {
            float2 kk = uph(kp[j * 256]);
            as += pq[slot][c * 32 + 2 * j] * kk.x + pq[slot][c * 32 + 2 * j + 1] * kk.y;
        }
        pA[c][vl] = make_float4(ai, af, acg, ao);
        pS[c][vl] = as;
        __syncthreads();

        if (tid < 128) {
            float4 A = pA[0][vl];
            float  S = pS[0][vl];
            #pragma unroll
            for (int cc = 1; cc < 8; ++cc) {
                float4 q = pA[cc][vl];
                A.x += q.x; A.y += q.y; A.z += q.z; A.w += q.w;
                S += pS[cc][vl];
            }
            float gi = sigmoidf_(xa.x + A.x);
            float gf = sigmoidf_(xa.y + A.y);
            float cb = tanhf_(xa.z + A.z);
            cst = gf * cst + gi * cb;
            float go = sigmoidf_(xa.w + A.w);
            float hh = go * tanhf_(cst);
            float hs = sigmoidf_(S + b2);
            float hf = s0 * hh + (1.f - s0) * hs;
            h4[voff + vl] = make_float4(gi, gf, cst, go);
            pq[slot][voff + vl] = hf;
            out[((size_t)pair * 128 + t) * 256 + voff + vl] = hf;
            // publish to partner (slot t&1)
            float* dst = EX + (((size_t)(t & 1) * 64 + pair) * 2 + half) * 640;
            union { float4 f4; unsigned long long u[2]; } gv;
            gv.f4 = make_float4(gi, gf, cst, go);
            __hip_atomic_store((unsigned long long*)dst + 2 * vl,     gv.u[0], __ATOMIC_RELAXED, __HIP_MEMORY_SCOPE_AGENT);
            __hip_atomic_store((unsigned long long*)dst + 2 * vl + 1, gv.u[1], __ATOMIC_RELAXED, __HIP_MEMORY_SCOPE_AGENT);
            __hip_atomic_store(dst + 512 + vl, hf, __ATOMIC_RELAXED, __HIP_MEMORY_SCOPE_AGENT);
        }
        __syncthreads();   // implicit vmcnt(0): data atomics completed before flag issues
        if (tid == 0)
            __hip_atomic_store(mflag, (unsigned)(t + 1), __ATOMIC_RELAXED, __HIP_MEMORY_SCOPE_AGENT);
    }
}

// ---------------- SD transpose: (64 x 32768) -> SDT (32768 x 64) ----------------
__global__ __launch_bounds__(256) void transp(const float* __restrict__ SD, float* __restrict__ SDT)
{
    const int k0 = blockIdx.x * 64;
    const int tid = threadIdx.x;
    __shared__ float t[64][65];
    #pragma unroll
    for (int i = 0; i < 4; ++i) {
        int idx = i * 256 + tid;
        int r = idx >> 4, c4 = (idx & 15) * 4;
        float4 x = *reinterpret_cast<const float4*>(SD + (size_t)r * 32768 + k0 + c4);
        t[r][c4] = x.x; t[r][c4 + 1] = x.y; t[r][c4 + 2] = x.z; t[r][c4 + 3] = x.w;
    }
    __syncthreads();
    #pragma unroll
    for (int i = 0; i < 4; ++i) {
        int idx = i * 256 + tid;
        int k = idx >> 4, r4 = (idx & 15) * 4;
        float4 o = make_float4(t[r4][k], t[r4 + 1][k], t[r4 + 2][k], t[r4 + 3][k]);
        *reinterpret_cast<float4*>(SDT + (size_t)(k0 + k) * 64 + r4) = o;
    }
}

// ---------------- dense split-K partials: grid = 64 col-tiles x 16 k-chunks ----------------
__global__ __launch_bounds__(256) void dense_partial(
    const float* __restrict__ SDT,   // (32768 x 64)
    const float* __restrict__ dw,    // (32768 x 4096)
    float* __restrict__ P)           // (16 x 64 x 4096)
{
    const int tid = threadIdx.x;
    const int ct = blockIdx.x & 63;
    const int kc = blockIdx.x >> 6;   // 0..15
    const int jq = tid & 15;
    const int rg = tid >> 4;
    const int j0 = ct * 64 + jq * 4;
    const int r0 = rg * 4;

    const float* sp = SDT + (size_t)kc * 2048 * 64 + r0;
    const float* wp = dw + (size_t)kc * 2048 * 4096 + j0;

    float4 a0 = make_float4(0.f,0.f,0.f,0.f), a1 = a0, a2 = a0, a3 = a0;
    #pragma unroll 8
    for (int kk = 0; kk < 2048; ++kk) {
        float4 s4 = *reinterpret_cast<const float4*>(sp + (size_t)kk * 64);
        float4 w4 = *reinterpret_cast<const float4*>(wp + (size_t)kk * 4096);
        a0.x += s4.x * w4.x; a0.y += s4.x * w4.y; a0.z += s4.x * w4.z; a0.w += s4.x * w4.w;
        a1.x += s4.y * w4.x; a1.y += s4.y * w4.y; a1.z += s4.y * w4.z; a1.w += s4.y * w4.w;
        a2.x += s4.z * w4.x; a2.y += s4.z * w4.y; a2.z += s4.z * w4.z; a2.w += s4.z * w4.w;
        a3.x += s4.w * w4.x; a3.y += s4.w * w4.y; a3.z += s4.w * w4.z; a3.w += s4.w * w4.w;
    }
    float* p0 = P + ((size_t)(kc * 64 + r0) * 4096) + j0;
    *reinterpret_cast<float4*>(p0)               = a0;
    *reinterpret_cast<float4*>(p0 + 4096)        = a1;
    *reinterpret_cast<float4*>(p0 + 2 * 4096)    = a2;
    *reinterpret_cast<float4*>(p0 + 3 * 4096)    = a3;
}

// ---------------- reduce partials + bias + Z2 ----------------
__global__ __launch_bounds__(256) void reduce_z2(
    const float* __restrict__ P,
    const float* __restrict__ db,
    const float* __restrict__ X,
    const float* __restrict__ fw,
    const float* __restrict__ fbp,
    float* __restrict__ out)
{
    const int o4 = blockIdx.x * 256 + threadIdx.x;   // 0..65535
    const int b  = o4 >> 10;
    const int j4 = o4 & 1023;
    const int j0 = j4 * 4;
    const int i  = j0 >> 5;
    const int m  = j0 & 31;

    float4 acc = *reinterpret_cast<const float4*>(db + j0);
    #pragma unroll
    for (int kc = 0; kc < 16; ++kc) {
        float4 p = *reinterpret_cast<const float4*>(P + (size_t)(kc * 64 + b) * 4096 + j0);
        acc.x += p.x; acc.y += p.y; acc.z += p.z; acc.w += p.w;
    }

    const float* xp = X + ((size_t)(b * 129 + 1 + i) * 128) * 32 + m;
    #pragma unroll 8
    for (int s = 0; s < 128; ++s) {
        float4 xv = *reinterpret_cast<const float4*>(xp + (size_t)s * 32);
        float w = fw[s];
        acc.x += w * xv.x; acc.y += w * xv.y; acc.z += w * xv.z; acc.w += w * xv.w;
    }
    const float fb = fbp[0];
    acc.x += fb; acc.y += fb; acc.z += fb; acc.w += fb;
    *reinterpret_cast<float4*>(out + (size_t)o4 * 4) = acc;
}

extern "C" void kernel_launch(void* const* d_in, const int* in_sizes, int n_in,
                              void* d_out, int out_size, void* d_ws, size_t ws_size,
                              hipStream_t stream) {
    const float* X    = (const float*)d_in[0];
    const float* e_k  = (const float*)d_in[1];
    const float* e_rk = (const float*)d_in[2];
    const float* e_k2 = (const float*)d_in[3];
    const float* e_b  = (const float*)d_in[4];
    const float* e_b2 = (const float*)d_in[5];
    const float* e_s0 = (const float*)d_in[6];
    const float* d_k  = (const float*)d_in[7];
    const float* d_rk = (const float*)d_in[8];
    const float* d_k2 = (const float*)d_in[9];
    const float* d_b  = (const float*)d_in[10];
    const float* d_b2 = (const float*)d_in[11];
    const float* d_s0 = (const float*)d_in[12];
    const float* dw   = (const float*)d_in[13];
    const float* db   = (const float*)d_in[14];
    const float* fw   = (const float*)d_in[15];
    const float* fb   = (const float*)d_in[16];

    float* ws = (float*)d_ws;
    // workspace (float offsets):
    // rk4e 0 | rk4d 262144 | dk4 524288 | ek4 786432(+32768; flags reuse its head after xw_enc)
    // kh2e 819200 | kh2d 851968 | EX 884736(+163840 -> 1048576)
    // xW 1048576 (8M, reused as P) | SE 9437184 (2M, reused as SDT) | SD 11534336 (2M)
    float4*   rk4e  = (float4*)(ws);
    float4*   rk4d  = (float4*)(ws + 262144);
    float4*   dk4   = (float4*)(ws + 524288);
    float4*   ek4   = (float4*)(ws + 786432);
    unsigned* flags = (unsigned*)(ws + 786432);   // ek4 dead after xw_gemm_enc
    unsigned* kh2e  = (unsigned*)(ws + 819200);
    unsigned* kh2d  = (unsigned*)(ws + 851968);
    float*    EX    = ws + 884736;
    float*    xW    = ws + 1048576;
    float*    SE    = ws + 9437184;
    float*    SD    = ws + 11534336;

    float* P   = xW;   // 16*64*4096 = 4M floats, xW dead by then
    float* SDT = SE;   // 32768*64 = 2M floats, SE dead by then

    hipLaunchKernelGGL(packall, dim3(928), dim3(256), 0, stream,
                       e_rk, d_rk, d_k, e_k, e_k2, d_k2,
                       rk4e, rk4d, dk4, ek4, kh2e, kh2d);
    hipLaunchKernelGGL(xw_gemm_enc, dim3(512), dim3(256), 0, stream,
                       X, ek4, e_b, (float4*)xW);
    hipLaunchKernelGGL(zero_ex, dim3(641), dim3(256), 0, stream, EX, flags);
    hipLaunchKernelGGL(rec4, dim3(128), dim3(1024), 0, stream,
                       (const float4*)xW, rk4e, kh2e, e_b2, e_s0, SE, EX, flags);
    hipLaunchKernelGGL(xw_gemm_dec, dim3(256), dim3(512), 0, stream,
                       SE, dk4, d_b, (float4*)xW);
    hipLaunchKernelGGL(zero_ex, dim3(641), dim3(256), 0, stream, EX, flags);
    hipLaunchKernelGGL(rec4, dim3(128), dim3(1024), 0, stream,
                       (const float4*)xW, rk4d, kh2d, d_b2, d_s0, SD, EX, flags);
    hipLaunchKernelGGL(transp, dim3(512), dim3(256), 0, stream, SD, SDT);
    hipLaunchKernelGGL(dense_partial, dim3(1024), dim3(256), 0, stream, SDT, dw, P);
    hipLaunchKernelGGL(reduce_z2, dim3(256), dim3(256), 0, stream,
                       P, db, X, fw, fb, (float*)d_out);
}

// Round 10
// 1727.178 us; speedup vs baseline: 6.3564x; 1.1682x over previous
//
#include <hip/hip_runtime.h>
#include <hip/hip_fp16.h>

// B=64, T=128, U=256, D_in=32, SKIP=4; dense: (64 x 32768) @ (32768 x 4096)

__device__ __forceinline__ float sigmoidf_(float x) {
    return 1.0f / (1.0f + __expf(-x));
}
__device__ __forceinline__ float tanhf_(float x) {
    float xc = fminf(fmaxf(x, -15.f), 15.f);
    float e = __expf(2.f * xc);
    return (e - 1.f) / (e + 1.f);
}
__device__ __forceinline__ unsigned pkh(float lo, float hi) {
    __half2 h = __halves2half2(__float2half(lo), __float2half(hi));
    return *reinterpret_cast<unsigned*>(&h);
}
__device__ __forceinline__ float2 uph(unsigned u) {
    __half2 h = *reinterpret_cast<__half2*>(&u);
    return __half22float2(h);
}

// ---------------- all weight packing in one dispatch ----------------
__global__ __launch_bounds__(256) void packall(
    const float* __restrict__ e_rk, const float* __restrict__ d_rk,
    const float* __restrict__ d_k,  const float* __restrict__ e_k,
    const float* __restrict__ e_k2, const float* __restrict__ d_k2,
    float4* __restrict__ rk4e, float4* __restrict__ rk4d,
    float4* __restrict__ dk4,  float4* __restrict__ ek4,
    unsigned* __restrict__ kh2e, unsigned* __restrict__ kh2d)
{
    const int bx = blockIdx.x, v = threadIdx.x;
    if (bx < 800) {
        const float* src; float4* dst; int row;
        if (bx < 256)      { src = e_rk; dst = rk4e; row = bx; }
        else if (bx < 512) { src = d_rk; dst = rk4d; row = bx - 256; }
        else if (bx < 768) { src = d_k;  dst = dk4;  row = bx - 512; }
        else               { src = e_k;  dst = ek4;  row = bx - 768; }
        const float* s = src + (size_t)row * 1024;
        dst[row * 256 + v] = make_float4(s[v], s[256 + v], s[512 + v], s[768 + v]);
    } else {
        const int u2 = bx - 800;   // 0..127
        kh2e[u2 * 256 + v] = pkh(e_k2[(2 * u2) * 256 + v], e_k2[(2 * u2 + 1) * 256 + v]);
        kh2d[u2 * 256 + v] = pkh(d_k2[(2 * u2) * 256 + v], d_k2[(2 * u2 + 1) * 256 + v]);
    }
}

// ---------------- enc xW GEMM: K=32 rows gathered from X[:,0] ----------------
__global__ __launch_bounds__(256) void xw_gemm_enc(
    const float*  __restrict__ X,
    const float4* __restrict__ ek4,
    const float*  __restrict__ bias,
    float4* __restrict__ xWp)
{
    const int v = threadIdx.x;
    const int r0 = blockIdx.x * 16;
    __shared__ float se[16][32];

    #pragma unroll
    for (int p = 0; p < 2; ++p) {
        int idx = p * 256 + v;
        int rr = idx >> 5, d = idx & 31;
        int R = r0 + rr, b = R >> 7, t = R & 127;
        se[rr][d] = X[((size_t)b * 129 * 128 + t) * 32 + d];   // X[b,0,t,d]
    }
    __syncthreads();

    float4 bv = make_float4(bias[v], bias[256 + v], bias[512 + v], bias[768 + v]);
    float4 acc[16];
    #pragma unroll
    for (int rr = 0; rr < 16; ++rr) acc[rr] = bv;

    #pragma unroll
    for (int u = 0; u < 32; ++u) {
        float4 w = ek4[u * 256 + v];
        #pragma unroll
        for (int rr = 0; rr < 16; ++rr) {
            float s = se[rr][u];
            acc[rr].x += s * w.x; acc[rr].y += s * w.y;
            acc[rr].z += s * w.z; acc[rr].w += s * w.w;
        }
    }
    #pragma unroll
    for (int rr = 0; rr < 16; ++rr)
        xWp[(size_t)(r0 + rr) * 256 + v] = acc[rr];
}

// ---------------- dec xW GEMM: 32 rows/block, 512 threads ----------------
__global__ __launch_bounds__(512) void xw_gemm_dec(
    const float*  __restrict__ SE,
    const float4* __restrict__ dk4,
    const float*  __restrict__ bias,
    float4* __restrict__ xWp)
{
    const int tid = threadIdx.x;
    const int v = tid & 255;
    const int hh = tid >> 8;               // 0/1
    const int rbase = blockIdx.x * 32;
    __shared__ float se[32][256];

    for (int i = tid; i < 8192; i += 512) {
        int rr = i >> 8, c = i & 255;
        se[rr][c] = SE[(size_t)(rbase + rr) * 256 + c];
    }
    __syncthreads();

    float4 bv = make_float4(bias[v], bias[256 + v], bias[512 + v], bias[768 + v]);
    float4 acc[16];
    #pragma unroll
    for (int rr = 0; rr < 16; ++rr) acc[rr] = bv;

    #pragma unroll 8
    for (int u = 0; u < 256; ++u) {
        float4 w = dk4[u * 256 + v];
        #pragma unroll
        for (int rr = 0; rr < 16; ++rr) {
            float s = se[hh * 16 + rr][u];
            acc[rr].x += s * w.x; acc[rr].y += s * w.y;
            acc[rr].z += s * w.z; acc[rr].w += s * w.w;
        }
    }
    #pragma unroll
    for (int rr = 0; rr < 16; ++rr)
        xWp[(size_t)(rbase + hh * 16 + rr) * 256 + v] = acc[rr];
}

// ---------------- zero exchange buffers + flags ----------------
// EX: 2 slots x 64 b x 4 slices x 320 floats = 327680 floats; flags: 256
__global__ __launch_bounds__(256) void zero_ex(float* __restrict__ EX, unsigned* __restrict__ flags)
{
    const int bx = blockIdx.x;
    if (bx < 1280) EX[bx * 256 + threadIdx.x] = 0.f;
    else flags[threadIdx.x] = 0u;
}

// ---------------- skip-LSTM recurrence: 256 blocks = 64 batches x 4 v-slices ----------------
// Each block: 1024 thr = 16 u-chunks x 64 v; 128 of 256 gate rows LDS-resident.
// Per-step 4-way exchange of {gate-vec float4[64], h float[64]} via relaxed agent-scope
// atomics (no fences). 2-slot parity protocol, flag = completed step count.
__global__ __launch_bounds__(1024) void rec5(
    const float4*   __restrict__ xW,    // (B*128*256) float4, bias included
    const float4*   __restrict__ rk4,   // (256*256) fp32 gate weights
    const unsigned* __restrict__ kh2,   // (128*256) fp16 skip-weight pairs
    const float*    __restrict__ bias2,
    const float*    __restrict__ s0p,
    float* __restrict__ out,            // (B*128*256)
    float* __restrict__ EX,             // [2][64][4][320] floats
    unsigned* __restrict__ flags)       // [64][4]
{
    const int b     = blockIdx.x >> 2;   // batch
    const int slice = blockIdx.x & 3;    // v-slice
    const int voff  = slice * 64;
    const int tid   = threadIdx.x;
    const int us    = tid >> 6;          // 0..15 u-chunk (16 u each)
    const int vl    = tid & 63;
    const int v     = voff + vl;

    __shared__ float4 wres[128][64];     // 128 KB: rows us*16+0..7 per chunk
    __shared__ float4 pA[16][64];        // 16 KB
    __shared__ float  pS[16][64];        // 4 KB
    __shared__ float4 h4[256];           // 4 KB: full gate state [i,f,c,o] by u
    __shared__ float  pq[4][256];        // 4 KB: full h ring

    for (int i = tid; i < 8192; i += 1024) {
        int r = i >> 6, vv = i & 63;
        int cc = r >> 3, j = r & 7;
        wres[r][vv] = rk4[(cc * 16 + j) * 256 + voff + vv];
    }
    if (tid < 256) {
        h4[tid] = make_float4(0.f, 0.f, 0.f, 0.f);
        pq[0][tid] = 0.f; pq[1][tid] = 0.f; pq[2][tid] = 0.f; pq[3][tid] = 0.f;
    }
    float cst = 0.f;
    const float s0 = s0p[0];
    const float b2 = bias2[voff + vl];
    unsigned* mflag = flags + b * 4 + slice;
    __syncthreads();

    for (int t = 0; t < 128; ++t) {
        // wait for all 3 partners to finish step t-1
        if (t > 0 && tid < 3) {
            int ps = tid + (tid >= slice ? 1 : 0);
            const unsigned* pf = flags + b * 4 + ps;
            while (__hip_atomic_load(pf, __ATOMIC_RELAXED, __HIP_MEMORY_SCOPE_AGENT) < (unsigned)t)
                __builtin_amdgcn_s_sleep(8);
        }
        __syncthreads();
        // stage partners' step-(t-1) state from slot (t-1)&1
        {
            const int sp = (t + 1) & 1;
            if (tid < 480) {
                int pi = tid / 160;                       // 0..2
                int j  = tid - pi * 160;                  // 0..159 (ull index)
                int ps = pi + (pi >= slice ? 1 : 0);
                const unsigned long long* src = (const unsigned long long*)
                    (EX + (((size_t)sp * 64 + b) * 4 + ps) * 320);
                unsigned long long d = __hip_atomic_load(src + j, __ATOMIC_RELAXED, __HIP_MEMORY_SCOPE_AGENT);
                if (j < 128) {
                    reinterpret_cast<unsigned long long*>(&h4[ps * 64])[j] = d;
                } else {
                    int k = j - 128;   // 0..31
                    union { unsigned long long u; float f[2]; } cv; cv.u = d;
                    pq[(t + 3) & 3][ps * 64 + 2 * k]     = cv.f[0];
                    pq[(t + 3) & 3][ps * 64 + 2 * k + 1] = cv.f[1];
                }
            }
        }
        float4 xa = make_float4(0.f, 0.f, 0.f, 0.f);
        if (tid < 64) xa = xW[((size_t)b * 128 + t) * 256 + voff + tid];
        __syncthreads();

        // GEMV: my 16-u chunk for my v column
        float ai = 0.f, af = 0.f, acg = 0.f, ao = 0.f, as = 0.f;
        #pragma unroll
        for (int j = 0; j < 8; ++j) {
            float4 w = wres[us * 8 + j][vl];
            float4 g = h4[us * 16 + j];
            ai += g.x * w.x; af += g.y * w.y; acg += g.z * w.z; ao += g.w * w.w;
        }
        const float4* wp = rk4 + (us * 16 + 8) * 256 + v;
        #pragma unroll
        for (int j = 0; j < 8; ++j) {
            float4 w = wp[j * 256];
            float4 g = h4[us * 16 + 8 + j];
            ai += g.x * w.x; af += g.y * w.y; acg += g.z * w.z; ao += g.w * w.w;
        }
        const unsigned* kp = kh2 + (us * 8) * 256 + v;
        const int slot = t & 3;
        #pragma unroll
        for (int j = 0; j < 8; ++j) {
            float2 kk = uph(kp[j * 256]);
            as += pq[slot][us * 16 + 2 * j] * kk.x + pq[slot][us * 16 + 2 * j + 1] * kk.y;
        }
        pA[us][vl] = make_float4(ai, af, acg, ao);
        pS[us][vl] = as;
        __syncthreads();

        if (tid < 64) {
            float4 A = pA[0][vl];
            float  S = pS[0][vl];
            #pragma unroll
            for (int cc = 1; cc < 16; ++cc) {
                float4 q = pA[cc][vl];
                A.x += q.x; A.y += q.y; A.z += q.z; A.w += q.w;
                S += pS[cc][vl];
            }
            float gi = sigmoidf_(xa.x + A.x);
            float gf = sigmoidf_(xa.y + A.y);
            float cb = tanhf_(xa.z + A.z);
            cst = gf * cst + gi * cb;
            float go = sigmoidf_(xa.w + A.w);
            float hh = go * tanhf_(cst);
            float hs = sigmoidf_(S + b2);
            float hf = s0 * hh + (1.f - s0) * hs;
            h4[voff + vl] = make_float4(gi, gf, cst, go);
            pq[slot][voff + vl] = hf;
            out[((size_t)b * 128 + t) * 256 + voff + vl] = hf;
            // publish to partners (slot t&1): 128 ull gates + 64 f h
            float* dst = EX + (((size_t)(t & 1) * 64 + b) * 4 + slice) * 320;
            union { float4 f4; unsigned long long u[2]; } gv;
            gv.f4 = make_float4(gi, gf, cst, go);
            __hip_atomic_store((unsigned long long*)dst + 2 * vl,     gv.u[0], __ATOMIC_RELAXED, __HIP_MEMORY_SCOPE_AGENT);
            __hip_atomic_store((unsigned long long*)dst + 2 * vl + 1, gv.u[1], __ATOMIC_RELAXED, __HIP_MEMORY_SCOPE_AGENT);
            __hip_atomic_store(dst + 256 + vl, hf, __ATOMIC_RELAXED, __HIP_MEMORY_SCOPE_AGENT);
        }
        __syncthreads();   // compiler drains vmcnt before s_barrier -> publishes visible
        if (tid == 0)
            __hip_atomic_store(mflag, (unsigned)(t + 1), __ATOMIC_RELAXED, __HIP_MEMORY_SCOPE_AGENT);
    }
}

// ---------------- SD transpose: (64 x 32768) -> SDT (32768 x 64) ----------------
__global__ __launch_bounds__(256) void transp(const float* __restrict__ SD, float* __restrict__ SDT)
{
    const int k0 = blockIdx.x * 64;
    const int tid = threadIdx.x;
    __shared__ float t[64][65];
    #pragma unroll
    for (int i = 0; i < 4; ++i) {
        int idx = i * 256 + tid;
        int r = idx >> 4, c4 = (idx & 15) * 4;
        float4 x = *reinterpret_cast<const float4*>(SD + (size_t)r * 32768 + k0 + c4);
        t[r][c4] = x.x; t[r][c4 + 1] = x.y; t[r][c4 + 2] = x.z; t[r][c4 + 3] = x.w;
    }
    __syncthreads();
    #pragma unroll
    for (int i = 0; i < 4; ++i) {
        int idx = i * 256 + tid;
        int k = idx >> 4, r4 = (idx & 15) * 4;
        float4 o = make_float4(t[r4][k], t[r4 + 1][k], t[r4 + 2][k], t[r4 + 3][k]);
        *reinterpret_cast<float4*>(SDT + (size_t)(k0 + k) * 64 + r4) = o;
    }
}

// ---------------- dense split-K partials: grid = 64 col-tiles x 16 k-chunks ----------------
__global__ __launch_bounds__(256) void dense_partial(
    const float* __restrict__ SDT,   // (32768 x 64)
    const float* __restrict__ dw,    // (32768 x 4096)
    float* __restrict__ P)           // (16 x 64 x 4096)
{
    const int tid = threadIdx.x;
    const int ct = blockIdx.x & 63;
    const int kc = blockIdx.x >> 6;   // 0..15
    const int jq = tid & 15;
    const int rg = tid >> 4;
    const int j0 = ct * 64 + jq * 4;
    const int r0 = rg * 4;

    const float* sp = SDT + (size_t)kc * 2048 * 64 + r0;
    const float* wp = dw + (size_t)kc * 2048 * 4096 + j0;

    float4 a0 = make_float4(0.f,0.f,0.f,0.f), a1 = a0, a2 = a0, a3 = a0;
    #pragma unroll 8
    for (int kk = 0; kk < 2048; ++kk) {
        float4 s4 = *reinterpret_cast<const float4*>(sp + (size_t)kk * 64);
        float4 w4 = *reinterpret_cast<const float4*>(wp + (size_t)kk * 4096);
        a0.x += s4.x * w4.x; a0.y += s4.x * w4.y; a0.z += s4.x * w4.z; a0.w += s4.x * w4.w;
        a1.x += s4.y * w4.x; a1.y += s4.y * w4.y; a1.z += s4.y * w4.z; a1.w += s4.y * w4.w;
        a2.x += s4.z * w4.x; a2.y += s4.z * w4.y; a2.z += s4.z * w4.z; a2.w += s4.z * w4.w;
        a3.x += s4.w * w4.x; a3.y += s4.w * w4.y; a3.z += s4.w * w4.z; a3.w += s4.w * w4.w;
    }
    float* p0 = P + ((size_t)(kc * 64 + r0) * 4096) + j0;
    *reinterpret_cast<float4*>(p0)               = a0;
    *reinterpret_cast<float4*>(p0 + 4096)        = a1;
    *reinterpret_cast<float4*>(p0 + 2 * 4096)    = a2;
    *reinterpret_cast<float4*>(p0 + 3 * 4096)    = a3;
}

// ---------------- reduce partials + bias + Z2 ----------------
__global__ __launch_bounds__(256) void reduce_z2(
    const float* __restrict__ P,
    const float* __restrict__ db,
    const float* __restrict__ X,
    const float* __restrict__ fw,
    const float* __restrict__ fbp,
    float* __restrict__ out)
{
    const int o4 = blockIdx.x * 256 + threadIdx.x;   // 0..65535
    const int b  = o4 >> 10;
    const int j4 = o4 & 1023;
    const int j0 = j4 * 4;
    const int i  = j0 >> 5;
    const int m  = j0 & 31;

    float4 acc = *reinterpret_cast<const float4*>(db + j0);
    #pragma unroll
    for (int kc = 0; kc < 16; ++kc) {
        float4 p = *reinterpret_cast<const float4*>(P + (size_t)(kc * 64 + b) * 4096 + j0);
        acc.x += p.x; acc.y += p.y; acc.z += p.z; acc.w += p.w;
    }

    const float* xp = X + ((size_t)(b * 129 + 1 + i) * 128) * 32 + m;
    #pragma unroll 8
    for (int s = 0; s < 128; ++s) {
        float4 xv = *reinterpret_cast<const float4*>(xp + (size_t)s * 32);
        float w = fw[s];
        acc.x += w * xv.x; acc.y += w * xv.y; acc.z += w * xv.z; acc.w += w * xv.w;
    }
    const float fb = fbp[0];
    acc.x += fb; acc.y += fb; acc.z += fb; acc.w += fb;
    *reinterpret_cast<float4*>(out + (size_t)o4 * 4) = acc;
}

extern "C" void kernel_launch(void* const* d_in, const int* in_sizes, int n_in,
                              void* d_out, int out_size, void* d_ws, size_t ws_size,
                              hipStream_t stream) {
    const float* X    = (const float*)d_in[0];
    const float* e_k  = (const float*)d_in[1];
    const float* e_rk = (const float*)d_in[2];
    const float* e_k2 = (const float*)d_in[3];
    const float* e_b  = (const float*)d_in[4];
    const float* e_b2 = (const float*)d_in[5];
    const float* e_s0 = (const float*)d_in[6];
    const float* d_k  = (const float*)d_in[7];
    const float* d_rk = (const float*)d_in[8];
    const float* d_k2 = (const float*)d_in[9];
    const float* d_b  = (const float*)d_in[10];
    const float* d_b2 = (const float*)d_in[11];
    const float* d_s0 = (const float*)d_in[12];
    const float* dw   = (const float*)d_in[13];
    const float* db   = (const float*)d_in[14];
    const float* fw   = (const float*)d_in[15];
    const float* fb   = (const float*)d_in[16];

    float* ws = (float*)d_ws;
    // workspace (float offsets):
    // rk4e 0 | rk4d 262144 | dk4 524288 | ek4 786432(+32768; flags reuse its head after xw_enc)
    // kh2e 819200 | kh2d 851968 | EX 884736(+327680 -> 1212416)
    // xW 1310720 (8M, reused as P) | SE 9699328 (2M, reused as SDT) | SD 11796480 (2M) -> 13893632
    float4*   rk4e  = (float4*)(ws);
    float4*   rk4d  = (float4*)(ws + 262144);
    float4*   dk4   = (float4*)(ws + 524288);
    float4*   ek4   = (float4*)(ws + 786432);
    unsigned* flags = (unsigned*)(ws + 786432);   // ek4 dead after xw_gemm_enc
    unsigned* kh2e  = (unsigned*)(ws + 819200);
    unsigned* kh2d  = (unsigned*)(ws + 851968);
    float*    EX    = ws + 884736;
    float*    xW    = ws + 1310720;
    float*    SE    = ws + 9699328;
    float*    SD    = ws + 11796480;

    float* P   = xW;   // 16*64*4096 = 4M floats, xW dead by then
    float* SDT = SE;   // 32768*64 = 2M floats, SE dead by then

    hipLaunchKernelGGL(packall, dim3(928), dim3(256), 0, stream,
                       e_rk, d_rk, d_k, e_k, e_k2, d_k2,
                       rk4e, rk4d, dk4, ek4, kh2e, kh2d);
    hipLaunchKernelGGL(xw_gemm_enc, dim3(512), dim3(256), 0, stream,
                       X, ek4, e_b, (float4*)xW);
    hipLaunchKernelGGL(zero_ex, dim3(1281), dim3(256), 0, stream, EX, flags);
    hipLaunchKernelGGL(rec5, dim3(256), dim3(1024), 0, stream,
                       (const float4*)xW, rk4e, kh2e, e_b2, e_s0, SE, EX, flags);
    hipLaunchKernelGGL(xw_gemm_dec, dim3(256), dim3(512), 0, stream,
                       SE, dk4, d_b, (float4*)xW);
    hipLaunchKernelGGL(zero_ex, dim3(1281), dim3(256), 0, stream, EX, flags);
    hipLaunchKernelGGL(rec5, dim3(256), dim3(1024), 0, stream,
                       (const float4*)xW, rk4d, kh2d, d_b2, d_s0, SD, EX, flags);
    hipLaunchKernelGGL(transp, dim3(512), dim3(256), 0, stream, SD, SDT);
    hipLaunchKernelGGL(dense_partial, dim3(1024), dim3(256), 0, stream, SDT, dw, P);
    hipLaunchKernelGGL(reduce_z2, dim3(256), dim3(256), 0, stream,
                       P, db, X, fw, fb, (float*)d_out);
}